// Round 9
// baseline (141.829 us; speedup 1.0000x reference)
//
#include <hip/hip_runtime.h>
#include <hip/hip_bf16.h>
#include <stdint.h>

#define DIM 1024
#define T_LEN 2048
#define NB 2
#define NH 16
#define HD 64
#define NQT 32      // 2048/64 q-tiles
#define NCHUNK 144  // sum over qt of ceil((qt+1)/4)

typedef float f32x4 __attribute__((ext_vector_type(4)));
typedef float f32x16 __attribute__((ext_vector_type(16)));
typedef __bf16 bf16x8 __attribute__((ext_vector_type(8)));
typedef __bf16 bf16x2 __attribute__((ext_vector_type(2)));
typedef unsigned int u32;
typedef unsigned int u32x4 __attribute__((ext_vector_type(4)));

__device__ __forceinline__ float sgnf(float v) {
    return (v > 0.f) ? 1.f : ((v < 0.f) ? -1.f : 0.f);
}

__device__ __forceinline__ float sigmoid_half(float v) {
    // sigmoid(0.5*v) = 1/(1 + 2^(-0.5*log2(e)*v))
    return __builtin_amdgcn_rcpf(1.f + __builtin_amdgcn_exp2f(-0.72134752f * v));
}

__device__ __forceinline__ u32 pack2(float p0, float p1) {
    bf16x2 t = {(__bf16)p0, (__bf16)p1};
    return __builtin_bit_cast(u32, t);
}

// async global -> LDS, 16B per lane; LDS dest is wave-uniform base + lane*16
__device__ __forceinline__ void gload16(const __bf16* g, __bf16* l) {
    __builtin_amdgcn_global_load_lds(
        (__attribute__((address_space(1))) void*)g,
        (__attribute__((address_space(3))) void*)l,
        16, 0, 0);
}

// ---------------- prepass: x(f32) -> Xb (bf16 row-major), Xt (bf16 [b][h][d][t], V-SIGN-GATED) ----------------
__global__ __launch_bounds__(256) void prep_kernel(
    const float* __restrict__ x, const float* __restrict__ bvv,
    __bf16* __restrict__ xb, __bf16* __restrict__ xt)
{
    __shared__ __align__(16) __bf16 tile[64][72];

    const int bid = blockIdx.x;
    const int h = bid & 15, tmp = bid >> 4, tt = tmp & 31, b = tmp >> 5;
    const int tid = threadIdx.x;
    const int r = tid >> 2, c0 = (tid & 3) * 16;

    const size_t rowbase = ((size_t)(b * T_LEN + tt * 64 + r)) * DIM + h * HD + c0;
    const float* xp = x + rowbase;

    __bf16 v[16];
    #pragma unroll
    for (int i = 0; i < 16; i += 4) {
        f32x4 f = *(const f32x4*)(xp + i);
        #pragma unroll
        for (int j = 0; j < 4; ++j) v[i + j] = (__bf16)f[j];
    }
    bf16x8 s0, s1;
    #pragma unroll
    for (int j = 0; j < 8; ++j) { s0[j] = v[j]; s1[j] = v[8 + j]; }
    *(bf16x8*)(xb + rowbase)     = s0;
    *(bf16x8*)(xb + rowbase + 8) = s1;
    *(bf16x8*)&tile[r][c0]     = s0;
    *(bf16x8*)&tile[r][c0 + 8] = s1;

    __syncthreads();

    const int d = tid >> 2, t0c = (tid & 3) * 16;
    const float g = sgnf(bvv[h * HD + d]);   // fold sign(bvv) into V source
    __bf16 ov[16];
    #pragma unroll
    for (int i = 0; i < 16; ++i) ov[i] = (__bf16)((float)tile[t0c + i][d] * g);
    bf16x8 o0, o1;
    #pragma unroll
    for (int j = 0; j < 8; ++j) { o0[j] = ov[j]; o1[j] = ov[8 + j]; }
    const size_t obase = ((size_t)((b * NH + h) * HD + d)) * T_LEN + tt * 64 + t0c;
    *(bf16x8*)(xt + obase)     = o0;
    *(bf16x8*)(xt + obase + 8) = o1;
}

// ---------------- main: split-kv chunks, 32x32 MFMA, atomic f32 accumulation ----------------
// Block = (bh, q-tile qt, kv-chunk of <=4 tiles). 4608 uniform blocks -> the
// scheduler backfills as chunks retire (fixes the r8 triangular-drain at 23%
// occupancy). Sigmoid attention has no softmax denominator, so kv-partial PV
// sums are exactly additive: each wave unsafeAtomicAdd's its 32q x 64d f32
// partial into out (zeroed by hipMemsetAsync each launch). No reduce epilogue.
// r8-proven pipeline: K 3-ring + V 2-ring, explicit vmcnt(2)/vmcnt(0) at body
// top (self-sufficient; never relies on compiler waits), pinned issue order.
__global__ __launch_bounds__(256, 4) void mba_main(
    const __bf16* __restrict__ xb, const __bf16* __restrict__ xt,
    const float* __restrict__ bvq, const float* __restrict__ bvk,
    float* __restrict__ out)
{
    __shared__ __align__(16) __bf16 Kb[3][64][64];   // 24 KB
    __shared__ __align__(16) __bf16 Vb[2][64][64];   // 16 KB

    const int bid = blockIdx.x;
    // chunk id -> (qt, chunk-start). Enumerated qt=31..0 so full 4-tile chunks
    // dispatch first (LPT). nc(qt) = ceil((qt+1)/4) = (qt+4)>>2.
    int rem = bid >> 5;
    int qt = 31;
    while (rem >= ((qt + 4) >> 2)) { rem -= (qt + 4) >> 2; --qt; }
    const int c4 = rem * 4;                       // first kv tile of this chunk
    const int CL = min(4, qt + 1 - c4);           // tiles in this chunk

    const int bh = bid & 31;                 // low bits -> XCD locality on (b,h)
    const int b = bh >> 4, h = bh & 15;
    const int q0 = qt * 64;

    const int tid = threadIdx.x;
    const int w = tid >> 6, l = tid & 63;
    const int c = l & 31, hi = l >> 5;
    const int qh = w & 1, sh = w >> 1;

    const size_t xb_bh = (size_t)b * T_LEN * DIM + h * HD;      // row stride DIM
    const size_t xt_bh = (size_t)((b * NH + h) * HD) * T_LEN;   // row stride T_LEN

    // staging: lane covers (row = r0 + l>>3, granule = l&7); source granule
    // pre-swizzled by row&7 (involution; fragment reads apply the same XOR)
    const int rr = l >> 3;
    const int sw = ((l & 7) ^ rr) << 3;

    auto STAGE_K = [&](int buf, int kvt) {   // 2 gload16 per wave
        const int kv0s = kvt * 64;
        #pragma unroll
        for (int pt = 0; pt < 2; ++pt) {
            const int r0 = w * 8 + pt * 32;
            gload16(xb + xb_bh + (size_t)(kv0s + r0 + rr) * DIM + sw, &Kb[buf][r0][0]);
        }
    };
    auto STAGE_V = [&](int buf, int kvt) {   // 2 gload16 per wave
        const int kv0s = kvt * 64;
        #pragma unroll
        for (int pt = 0; pt < 2; ++pt) {
            const int r0 = w * 8 + pt * 32;
            gload16(xt + xt_bh + (size_t)(r0 + rr) * T_LEN + kv0s + sw, &Vb[buf][r0][0]);
        }
    };

    // prologue order matters for the vmcnt invariant: K0, V0, then K1
    STAGE_K(0, c4);
    STAGE_V(0, c4);
    if (CL >= 2) STAGE_K(1, c4 + 1);

    // ---- Q fragments (B-operand): col=lane&31=q, k=(lane>>5)*8+j over 4 k-steps ----
    bf16x8 qa[4];
    {
        const float* bq = bvq + h * HD;
        const float* bk = bvk + h * HD;
        const int qrow = q0 + qh * 32 + c;
        #pragma unroll
        for (int m = 0; m < 4; ++m) {
            const int d0 = m * 16 + hi * 8;
            bf16x8 va = *(const bf16x8*)(xb + xb_bh + (size_t)qrow * DIM + d0);
            #pragma unroll
            for (int j = 0; j < 8; ++j) {
                float f = sgnf(bq[d0 + j]) * sgnf(bk[d0 + j]);
                qa[m][j] = (__bf16)((float)va[j] * f);
            }
        }
    }

    f32x16 o[2];
    #pragma unroll
    for (int nd = 0; nd < 2; ++nd)
        #pragma unroll
        for (int i = 0; i < 16; ++i) o[nd][i] = 0.f;

    int cur = 0;
    const int krow = sh * 32 + c;      // A-operand row for S^T (s index)
    const int swz = (c & 7) << 4;      // fragment-read deswizzle (row&7 == c&7)

    for (int lt = 0; lt < CL; ++lt) {
        const int gt = c4 + lt;                 // global kv tile
        const bool last_local = (lt == CL - 1);
        const bool diag = (gt == qt);           // only in the final chunk
        // SELF-SUFFICIENT wait: at body top only K_{lt+1}x2 may stay in flight.
        if (last_local) { asm volatile("s_waitcnt vmcnt(0)" ::: "memory"); }
        else            { asm volatile("s_waitcnt vmcnt(2)" ::: "memory"); }
        __builtin_amdgcn_sched_barrier(0);
        __builtin_amdgcn_s_barrier();
        __builtin_amdgcn_sched_barrier(0);

        // ---- prefetch: V(lt+1) FIRST, then K(lt+2); order pinned ----
        if (lt + 1 < CL) STAGE_V((lt + 1) & 1, gt + 1);
        __builtin_amdgcn_sched_barrier(0);
        if (lt + 2 < CL) {
            int stg = cur + 2; if (stg >= 3) stg -= 3;
            STAGE_K(stg, gt + 2);
        }
        __builtin_amdgcn_sched_barrier(0);

        // ---- S^T = K Q^T : D[s=(r&3)+8(r>>2)+4hi (+32sh)][q = qh*32+c] ----
        f32x16 ss;
        #pragma unroll
        for (int i = 0; i < 16; ++i) ss[i] = 0.f;
        #pragma unroll
        for (int m = 0; m < 4; ++m) {
            bf16x8 kf = *(const bf16x8*)((const char*)&Kb[cur][krow][0]
                          + ((m * 32 + hi * 16) ^ swz));
            ss = __builtin_amdgcn_mfma_f32_32x32x16_bf16(kf, qa[m], ss, 0, 0, 0);
        }

        // ---- sigmoid + causal mask -> 8 packed words (s-pairs, this lane's q) ----
        u32 W[8];
        #pragma unroll
        for (int i = 0; i < 8; ++i) {
            const int r0 = 2 * i;
            const int sl = (r0 & 3) + 8 * (r0 >> 2) + 4 * hi;   // s_loc of reg r0
            float p0 = sigmoid_half(ss[r0]);
            float p1 = sigmoid_half(ss[r0 + 1]);
            if (diag) {
                const int sg = sh * 32 + sl;
                const int qg = qh * 32 + c;
                if (sg > qg)     p0 = 0.f;
                if (sg + 1 > qg) p1 = 0.f;
            }
            W[i] = pack2(p0, p1);
        }

        // ---- in-register transpose: 4x permlane32_swap assembles A-fragments ----
        asm volatile("v_permlane32_swap_b32 %0, %1" : "+v"(W[0]), "+v"(W[2]));
        asm volatile("v_permlane32_swap_b32 %0, %1" : "+v"(W[1]), "+v"(W[3]));
        asm volatile("v_permlane32_swap_b32 %0, %1" : "+v"(W[4]), "+v"(W[6]));
        asm volatile("v_permlane32_swap_b32 %0, %1" : "+v"(W[5]), "+v"(W[7]));
        bf16x8 pa[2];
        pa[0] = __builtin_bit_cast(bf16x8, (u32x4){W[0], W[1], W[2], W[3]});
        pa[1] = __builtin_bit_cast(bf16x8, (u32x4){W[4], W[5], W[6], W[7]});

        // ---- O += P V : A=P (row=q, k=s), B=V rows of Vb (col=d, k=s) ----
        // V's s-dim is the COLUMN of Vb[d][s]: the wave's s-half offset sh*64
        // bytes lives in the column offset (K carries sh in its ROW instead).
        #pragma unroll
        for (int m = 0; m < 2; ++m) {
            #pragma unroll
            for (int nd = 0; nd < 2; ++nd) {
                bf16x8 vf = *(const bf16x8*)((const char*)&Vb[lt & 1][nd * 32 + c][0]
                              + ((sh * 64 + m * 32 + hi * 16) ^ swz));
                o[nd] = __builtin_amdgcn_mfma_f32_32x32x16_bf16(pa[m], vf, o[nd], 0, 0, 0);
            }
        }
        cur = (cur == 2) ? 0 : cur + 1;
    }

    // ---- epilogue: atomic f32 accumulation (sign(bvv) pre-folded into xt) ----
    #pragma unroll
    for (int r = 0; r < 16; ++r) {
        const int qloc = (r & 3) + 8 * (r >> 2) + 4 * hi;
        float* op = out + (size_t)(b * T_LEN + q0 + qh * 32 + qloc) * DIM + h * HD + c;
        unsafeAtomicAdd(op,      o[0][r]);
        unsafeAtomicAdd(op + 32, o[1][r]);
    }
}

// ---------------- fallback (round-1 kernel) if ws too small ----------------
__global__ __launch_bounds__(256) void mba_fallback(
    const float* __restrict__ x,
    const float* __restrict__ bvq,
    const float* __restrict__ bvk,
    const float* __restrict__ bvv,
    float* __restrict__ out)
{
    __shared__ __align__(16) __bf16 Kb[64][72];
    __shared__ __align__(16) __bf16 Vt[HD][72];
    __shared__ __align__(16) __bf16 Pb[4][16][72];

    const int bid = blockIdx.x;
    const int qt  = (NQT - 1) - (bid & (NQT - 1));
    const int bh  = bid >> 5;
    const int b   = bh >> 4;
    const int h   = bh & 15;

    const int tid = threadIdx.x;
    const int w   = tid >> 6;
    const int l   = tid & 63;
    const int lq  = l & 15;
    const int lh  = l >> 4;

    const int  q0    = qt * 64;
    const long xbase = ((long)b * T_LEN) * DIM + h * HD;

    bf16x8 qa[2];
    {
        const int   qrow = q0 + w * 16 + lq;
        const float* qp  = x + xbase + (long)qrow * DIM + lh * 8;
        const float* gp  = bvq + h * HD + lh * 8;
        #pragma unroll
        for (int ks = 0; ks < 2; ++ks)
            #pragma unroll
            for (int j = 0; j < 8; ++j)
                qa[ks][j] = (__bf16)(qp[ks * 32 + j] * sgnf(gp[ks * 32 + j]));
    }

    f32x4 o[4];
    #pragma unroll
    for (int n = 0; n < 4; ++n) o[n] = (f32x4){0.f, 0.f, 0.f, 0.f};

    const int r_st = tid >> 2;
    const int c0   = (tid & 3) * 16;
    const float* gk = bvk + h * HD + c0;
    const float* gv = bvv + h * HD + c0;

    for (int kvt = 0; kvt <= qt; ++kvt) {
        const int kv0 = kvt * 64;
        __syncthreads();
        {
            const float* kp = x + xbase + (long)(kv0 + r_st) * DIM + c0;
            __bf16 kb[16];
            #pragma unroll
            for (int i = 0; i < 16; ++i) kb[i] = (__bf16)(kp[i] * sgnf(gk[i]));
            *(bf16x8*)&Kb[r_st][c0]     = *(bf16x8*)&kb[0];
            *(bf16x8*)&Kb[r_st][c0 + 8] = *(bf16x8*)&kb[8];
            #pragma unroll
            for (int i = 0; i < 16; ++i)
                Vt[c0 + i][r_st] = (__bf16)(kp[i] * sgnf(gv[i]));
        }
        __syncthreads();

        f32x4 s[4];
        #pragma unroll
        for (int n = 0; n < 4; ++n) s[n] = (f32x4){0.f, 0.f, 0.f, 0.f};
        #pragma unroll
        for (int ks = 0; ks < 2; ++ks)
            #pragma unroll
            for (int n = 0; n < 4; ++n) {
                bf16x8 kf = *(const bf16x8*)&Kb[n * 16 + lq][ks * 32 + lh * 8];
                s[n] = __builtin_amdgcn_mfma_f32_16x16x32_bf16(qa[ks], kf, s[n], 0, 0, 0);
            }

        const bool diag = (kvt == qt);
        #pragma unroll
        for (int n = 0; n < 4; ++n)
            #pragma unroll
            for (int j = 0; j < 4; ++j) {
                float p = sigmoid_half(s[n][j]);
                if (diag && (n * 16 + lq) > (w * 16 + lh * 4 + j)) p = 0.f;
                Pb[w][lh * 4 + j][n * 16 + lq] = (__bf16)p;
            }

        #pragma unroll
        for (int ks = 0; ks < 2; ++ks) {
            bf16x8 pf = *(const bf16x8*)&Pb[w][lq][ks * 32 + lh * 8];
            #pragma unroll
            for (int n = 0; n < 4; ++n) {
                bf16x8 vf = *(const bf16x8*)&Vt[n * 16 + lq][ks * 32 + lh * 8];
                o[n] = __builtin_amdgcn_mfma_f32_16x16x32_bf16(pf, vf, o[n], 0, 0, 0);
            }
        }
    }

    float* op = out + ((long)b * T_LEN + q0 + w * 16) * DIM + h * HD;
    #pragma unroll
    for (int n = 0; n < 4; ++n)
        #pragma unroll
        for (int j = 0; j < 4; ++j)
            op[(long)(lh * 4 + j) * DIM + n * 16 + lq] = o[n][j];
}

extern "C" void kernel_launch(void* const* d_in, const int* in_sizes, int n_in,
                              void* d_out, int out_size, void* d_ws, size_t ws_size,
                              hipStream_t stream) {
    (void)in_sizes; (void)n_in;
    const float* x   = (const float*)d_in[0];
    const float* bvq = (const float*)d_in[1];
    const float* bvk = (const float*)d_in[2];
    const float* bvv = (const float*)d_in[3];
    float* out = (float*)d_out;

    const size_t XB_BYTES = (size_t)NB * T_LEN * DIM * sizeof(__bf16);  // 8 MB
    const size_t XT_BYTES = XB_BYTES;                                    // 8 MB

    if (ws_size < XB_BYTES + XT_BYTES) {
        mba_fallback<<<NB * NH * NQT, 256, 0, stream>>>(x, bvq, bvk, bvv, out);
        return;
    }

    __bf16* xb = (__bf16*)d_ws;
    __bf16* xt = xb + (size_t)NB * T_LEN * DIM;

    hipMemsetAsync(d_out, 0, (size_t)out_size * sizeof(float), stream);
    prep_kernel<<<NB * NQT * NH, 256, 0, stream>>>(x, bvv, xb, xt);
    mba_main<<<NCHUNK * 32, 256, 0, stream>>>(xb, xt, bvq, bvk, out);
}

// Round 10
// 52.939 us; speedup vs baseline: 2.6791x; 2.6791x over previous
//
#include <hip/hip_runtime.h>
#include <hip/hip_bf16.h>
#include <stdint.h>

#define DIM 1024
#define T_LEN 2048
#define NB 2
#define NH 16
#define HD 64
#define NQT 32   // 2048/64 q-tiles

typedef float f32x4 __attribute__((ext_vector_type(4)));
typedef float f32x16 __attribute__((ext_vector_type(16)));
typedef __bf16 bf16x8 __attribute__((ext_vector_type(8)));
typedef __bf16 bf16x2 __attribute__((ext_vector_type(2)));
typedef unsigned int u32;
typedef unsigned int u32x4 __attribute__((ext_vector_type(4)));

__device__ __forceinline__ float sgnf(float v) {
    return (v > 0.f) ? 1.f : ((v < 0.f) ? -1.f : 0.f);
}

__device__ __forceinline__ float sigmoid_half(float v) {
    // sigmoid(0.5*v) = 1/(1 + 2^(-0.5*log2(e)*v))
    return __builtin_amdgcn_rcpf(1.f + __builtin_amdgcn_exp2f(-0.72134752f * v));
}

__device__ __forceinline__ u32 pack2(float p0, float p1) {
    bf16x2 t = {(__bf16)p0, (__bf16)p1};
    return __builtin_bit_cast(u32, t);
}

// async global -> LDS, 16B per lane; LDS dest is wave-uniform base + lane*16
__device__ __forceinline__ void gload16(const __bf16* g, __bf16* l) {
    __builtin_amdgcn_global_load_lds(
        (__attribute__((address_space(1))) void*)g,
        (__attribute__((address_space(3))) void*)l,
        16, 0, 0);
}

// ---------------- prepass: x(f32) -> Xb (bf16 row-major), Xt (bf16 [b][h][d][t], V-SIGN-GATED) ----------------
__global__ __launch_bounds__(256) void prep_kernel(
    const float* __restrict__ x, const float* __restrict__ bvv,
    __bf16* __restrict__ xb, __bf16* __restrict__ xt)
{
    __shared__ __align__(16) __bf16 tile[64][72];

    const int bid = blockIdx.x;
    const int h = bid & 15, tmp = bid >> 4, tt = tmp & 31, b = tmp >> 5;
    const int tid = threadIdx.x;
    const int r = tid >> 2, c0 = (tid & 3) * 16;

    const size_t rowbase = ((size_t)(b * T_LEN + tt * 64 + r)) * DIM + h * HD + c0;
    const float* xp = x + rowbase;

    __bf16 v[16];
    #pragma unroll
    for (int i = 0; i < 16; i += 4) {
        f32x4 f = *(const f32x4*)(xp + i);
        #pragma unroll
        for (int j = 0; j < 4; ++j) v[i + j] = (__bf16)f[j];
    }
    bf16x8 s0, s1;
    #pragma unroll
    for (int j = 0; j < 8; ++j) { s0[j] = v[j]; s1[j] = v[8 + j]; }
    *(bf16x8*)(xb + rowbase)     = s0;
    *(bf16x8*)(xb + rowbase + 8) = s1;
    *(bf16x8*)&tile[r][c0]     = s0;
    *(bf16x8*)&tile[r][c0 + 8] = s1;

    __syncthreads();

    const int d = tid >> 2, t0c = (tid & 3) * 16;
    const float g = sgnf(bvv[h * HD + d]);   // fold sign(bvv) into V source
    __bf16 ov[16];
    #pragma unroll
    for (int i = 0; i < 16; ++i) ov[i] = (__bf16)((float)tile[t0c + i][d] * g);
    bf16x8 o0, o1;
    #pragma unroll
    for (int j = 0; j < 8; ++j) { o0[j] = ov[j]; o1[j] = ov[8 + j]; }
    const size_t obase = ((size_t)((b * NH + h) * HD + d)) * T_LEN + tt * 64 + t0c;
    *(bf16x8*)(xt + obase)     = o0;
    *(bf16x8*)(xt + obase + 8) = o1;
}

// ---------------- main: paired q-tiles (uniform 33 units/block), 32x32 MFMA ----------------
// Block = (bh, p): q-tiles qtA=31-p (heavy) and qtB=p (light). kv range 0..qtA;
// while t<=qtB BOTH q-tiles consume the SAME staged tile and the SAME kf/vf
// LDS reads (dual bodies: 16 MFMA per 8 fragment reads). Every block = exactly
// 33 MFMA-units -> 512 blocks = 2/CU co-resident, zero tail drain (r8's 23%
// occupancy was the triangular drain; r9's atomics fix was HBM-bound).
// r8-proven pipeline verbatim: K 3-ring + V 2-ring, explicit vmcnt(2)/vmcnt(0)
// self-sufficient waits, pinned issue order V(t+1) then K(t+2).
__global__ __launch_bounds__(256, 2) void mba_main(
    const __bf16* __restrict__ xb, const __bf16* __restrict__ xt,
    const float* __restrict__ bvq, const float* __restrict__ bvk,
    float* __restrict__ out)
{
    __shared__ __align__(16) __bf16 Kb[3][64][64];   // 24 KB
    __shared__ __align__(16) __bf16 Vb[2][64][64];   // 16 KB

    const int bid = blockIdx.x;
    const int p = bid >> 5;                  // 0..15
    const int bh = bid & 31;                 // low bits -> XCD locality on (b,h)
    const int b = bh >> 4, h = bh & 15;
    const int qtA = 31 - p, qtB = p;         // qtA >= 16 > 15 >= qtB
    const int q0A = qtA * 64, q0B = qtB * 64;

    const int tid = threadIdx.x;
    const int w = tid >> 6, l = tid & 63;
    const int c = l & 31, hi = l >> 5;
    const int qh = w & 1, sh = w >> 1;

    const size_t xb_bh = (size_t)b * T_LEN * DIM + h * HD;      // row stride DIM
    const size_t xt_bh = (size_t)((b * NH + h) * HD) * T_LEN;   // row stride T_LEN

    // staging: lane covers (row = r0 + l>>3, granule = l&7); source granule
    // pre-swizzled by row&7 (involution; fragment reads apply the same XOR)
    const int rr = l >> 3;
    const int sw = ((l & 7) ^ rr) << 3;

    auto STAGE_K = [&](int buf, int kvt) {   // 2 gload16 per wave
        const int kv0s = kvt * 64;
        #pragma unroll
        for (int pt = 0; pt < 2; ++pt) {
            const int r0 = w * 8 + pt * 32;
            gload16(xb + xb_bh + (size_t)(kv0s + r0 + rr) * DIM + sw, &Kb[buf][r0][0]);
        }
    };
    auto STAGE_V = [&](int buf, int kvt) {   // 2 gload16 per wave
        const int kv0s = kvt * 64;
        #pragma unroll
        for (int pt = 0; pt < 2; ++pt) {
            const int r0 = w * 8 + pt * 32;
            gload16(xt + xt_bh + (size_t)(r0 + rr) * T_LEN + kv0s + sw, &Vb[buf][r0][0]);
        }
    };

    // prologue order matters for the vmcnt invariant: K0, V0, then K1 (qtA>=16)
    STAGE_K(0, 0);
    STAGE_V(0, 0);
    STAGE_K(1, 1);

    // ---- Q fragments for BOTH tiles (B-operand): col=q, k=(l>>5)*8+j ----
    bf16x8 qaA[4], qaB[4];
    {
        const float* bq = bvq + h * HD;
        const float* bk = bvk + h * HD;
        #pragma unroll
        for (int m = 0; m < 4; ++m) {
            const int d0 = m * 16 + hi * 8;
            bf16x8 va = *(const bf16x8*)(xb + xb_bh + (size_t)(q0A + qh * 32 + c) * DIM + d0);
            bf16x8 vb = *(const bf16x8*)(xb + xb_bh + (size_t)(q0B + qh * 32 + c) * DIM + d0);
            #pragma unroll
            for (int j = 0; j < 8; ++j) {
                float f = sgnf(bq[d0 + j]) * sgnf(bk[d0 + j]);
                qaA[m][j] = (__bf16)((float)va[j] * f);
                qaB[m][j] = (__bf16)((float)vb[j] * f);
            }
        }
    }

    f32x16 oA[2], oB[2];
    #pragma unroll
    for (int nd = 0; nd < 2; ++nd)
        #pragma unroll
        for (int i = 0; i < 16; ++i) { oA[nd][i] = 0.f; oB[nd][i] = 0.f; }

    int cur = 0;
    const int krow = sh * 32 + c;      // A-operand row for S^T (s index)
    const int swz = (c & 7) << 4;      // fragment-read deswizzle (row&7 == c&7)

    // sigmoid+mask+transpose: ss -> pa (in-register P A-fragments)
    auto makeP = [&](const f32x16& ss, bool diag, bf16x8* pa) {
        u32 W[8];
        #pragma unroll
        for (int i = 0; i < 8; ++i) {
            const int r0 = 2 * i;
            const int sl = (r0 & 3) + 8 * (r0 >> 2) + 4 * hi;   // s_loc of reg r0
            float p0 = sigmoid_half(ss[r0]);
            float p1 = sigmoid_half(ss[r0 + 1]);
            if (diag) {
                const int sg = sh * 32 + sl;
                const int qg = qh * 32 + c;
                if (sg > qg)     p0 = 0.f;
                if (sg + 1 > qg) p1 = 0.f;
            }
            W[i] = pack2(p0, p1);
        }
        asm volatile("v_permlane32_swap_b32 %0, %1" : "+v"(W[0]), "+v"(W[2]));
        asm volatile("v_permlane32_swap_b32 %0, %1" : "+v"(W[1]), "+v"(W[3]));
        asm volatile("v_permlane32_swap_b32 %0, %1" : "+v"(W[4]), "+v"(W[6]));
        asm volatile("v_permlane32_swap_b32 %0, %1" : "+v"(W[5]), "+v"(W[7]));
        pa[0] = __builtin_bit_cast(bf16x8, (u32x4){W[0], W[1], W[2], W[3]});
        pa[1] = __builtin_bit_cast(bf16x8, (u32x4){W[4], W[5], W[6], W[7]});
    };

    for (int t = 0; t <= qtA; ++t) {
        const bool last = (t == qtA);
        const bool dual = (t <= qtB);
        // SELF-SUFFICIENT wait: at body top only K_{t+1}x2 may stay in flight.
        if (last) { asm volatile("s_waitcnt vmcnt(0)" ::: "memory"); }
        else      { asm volatile("s_waitcnt vmcnt(2)" ::: "memory"); }
        __builtin_amdgcn_sched_barrier(0);
        __builtin_amdgcn_s_barrier();
        __builtin_amdgcn_sched_barrier(0);

        // ---- prefetch: V(t+1) FIRST, then K(t+2); order pinned ----
        if (t + 1 <= qtA) STAGE_V((t + 1) & 1, t + 1);
        __builtin_amdgcn_sched_barrier(0);
        if (t + 2 <= qtA) {
            int stg = cur + 2; if (stg >= 3) stg -= 3;
            STAGE_K(stg, t + 2);
        }
        __builtin_amdgcn_sched_barrier(0);

        // ---- S^T = K Q^T for both tiles (kf reads shared) ----
        f32x16 ssA, ssB;
        #pragma unroll
        for (int i = 0; i < 16; ++i) { ssA[i] = 0.f; ssB[i] = 0.f; }
        #pragma unroll
        for (int m = 0; m < 4; ++m) {
            bf16x8 kf = *(const bf16x8*)((const char*)&Kb[cur][krow][0]
                          + ((m * 32 + hi * 16) ^ swz));
            ssA = __builtin_amdgcn_mfma_f32_32x32x16_bf16(kf, qaA[m], ssA, 0, 0, 0);
            if (dual)
                ssB = __builtin_amdgcn_mfma_f32_32x32x16_bf16(kf, qaB[m], ssB, 0, 0, 0);
        }

        // ---- P fragments in-register (A always; B in dual bodies) ----
        bf16x8 paA[2], paB[2];
        makeP(ssA, last, paA);                       // diag for A only at t==qtA
        if (dual) makeP(ssB, t == qtB, paB);         // diag for B at t==qtB

        // ---- O += P V (vf reads shared) ----
        #pragma unroll
        for (int m = 0; m < 2; ++m) {
            #pragma unroll
            for (int nd = 0; nd < 2; ++nd) {
                bf16x8 vf = *(const bf16x8*)((const char*)&Vb[t & 1][nd * 32 + c][0]
                              + ((sh * 64 + m * 32 + hi * 16) ^ swz));
                oA[nd] = __builtin_amdgcn_mfma_f32_32x32x16_bf16(paA[m], vf, oA[nd], 0, 0, 0);
                if (dual)
                    oB[nd] = __builtin_amdgcn_mfma_f32_32x32x16_bf16(paB[m], vf, oB[nd], 0, 0, 0);
            }
        }
        cur = (cur == 2) ? 0 : cur + 1;
    }

    // ---- epilogue: reduce s-halves through LDS scratch, store (bvv folded) ----
    __syncthreads();                               // all ring reads/DMA done
    float (*osc)[64] = (float(*)[64]) & Kb[0][0][0];   // 16 KB scratch

    // tile A
    if (sh == 1) {
        #pragma unroll
        for (int r = 0; r < 16; ++r) {
            const int qloc = (r & 3) + 8 * (r >> 2) + 4 * hi;
            osc[qh * 32 + qloc][c]      = oA[0][r];
            osc[qh * 32 + qloc][32 + c] = oA[1][r];
        }
    }
    __syncthreads();
    if (sh == 0) {
        #pragma unroll
        for (int r = 0; r < 16; ++r) {
            const int qloc = (r & 3) + 8 * (r >> 2) + 4 * hi;
            const size_t row = (size_t)(b * T_LEN + q0A + qh * 32 + qloc) * DIM + h * HD;
            out[row + c]      = oA[0][r] + osc[qh * 32 + qloc][c];
            out[row + 32 + c] = oA[1][r] + osc[qh * 32 + qloc][32 + c];
        }
    }
    __syncthreads();
    // tile B
    if (sh == 1) {
        #pragma unroll
        for (int r = 0; r < 16; ++r) {
            const int qloc = (r & 3) + 8 * (r >> 2) + 4 * hi;
            osc[qh * 32 + qloc][c]      = oB[0][r];
            osc[qh * 32 + qloc][32 + c] = oB[1][r];
        }
    }
    __syncthreads();
    if (sh == 0) {
        #pragma unroll
        for (int r = 0; r < 16; ++r) {
            const int qloc = (r & 3) + 8 * (r >> 2) + 4 * hi;
            const size_t row = (size_t)(b * T_LEN + q0B + qh * 32 + qloc) * DIM + h * HD;
            out[row + c]      = oB[0][r] + osc[qh * 32 + qloc][c];
            out[row + 32 + c] = oB[1][r] + osc[qh * 32 + qloc][32 + c];
        }
    }
}

// ---------------- fallback (round-1 kernel) if ws too small ----------------
__global__ __launch_bounds__(256) void mba_fallback(
    const float* __restrict__ x,
    const float* __restrict__ bvq,
    const float* __restrict__ bvk,
    const float* __restrict__ bvv,
    float* __restrict__ out)
{
    __shared__ __align__(16) __bf16 Kb[64][72];
    __shared__ __align__(16) __bf16 Vt[HD][72];
    __shared__ __align__(16) __bf16 Pb[4][16][72];

    const int bid = blockIdx.x;
    const int qt  = (NQT - 1) - (bid & (NQT - 1));
    const int bh  = bid >> 5;
    const int b   = bh >> 4;
    const int h   = bh & 15;

    const int tid = threadIdx.x;
    const int w   = tid >> 6;
    const int l   = tid & 63;
    const int lq  = l & 15;
    const int lh  = l >> 4;

    const int  q0    = qt * 64;
    const long xbase = ((long)b * T_LEN) * DIM + h * HD;

    bf16x8 qa[2];
    {
        const int   qrow = q0 + w * 16 + lq;
        const float* qp  = x + xbase + (long)qrow * DIM + lh * 8;
        const float* gp  = bvq + h * HD + lh * 8;
        #pragma unroll
        for (int ks = 0; ks < 2; ++ks)
            #pragma unroll
            for (int j = 0; j < 8; ++j)
                qa[ks][j] = (__bf16)(qp[ks * 32 + j] * sgnf(gp[ks * 32 + j]));
    }

    f32x4 o[4];
    #pragma unroll
    for (int n = 0; n < 4; ++n) o[n] = (f32x4){0.f, 0.f, 0.f, 0.f};

    const int r_st = tid >> 2;
    const int c0   = (tid & 3) * 16;
    const float* gk = bvk + h * HD + c0;
    const float* gv = bvv + h * HD + c0;

    for (int kvt = 0; kvt <= qt; ++kvt) {
        const int kv0 = kvt * 64;
        __syncthreads();
        {
            const float* kp = x + xbase + (long)(kv0 + r_st) * DIM + c0;
            __bf16 kb[16];
            #pragma unroll
            for (int i = 0; i < 16; ++i) kb[i] = (__bf16)(kp[i] * sgnf(gk[i]));
            *(bf16x8*)&Kb[r_st][c0]     = *(bf16x8*)&kb[0];
            *(bf16x8*)&Kb[r_st][c0 + 8] = *(bf16x8*)&kb[8];
            #pragma unroll
            for (int i = 0; i < 16; ++i)
                Vt[c0 + i][r_st] = (__bf16)(kp[i] * sgnf(gv[i]));
        }
        __syncthreads();

        f32x4 s[4];
        #pragma unroll
        for (int n = 0; n < 4; ++n) s[n] = (f32x4){0.f, 0.f, 0.f, 0.f};
        #pragma unroll
        for (int ks = 0; ks < 2; ++ks)
            #pragma unroll
            for (int n = 0; n < 4; ++n) {
                bf16x8 kf = *(const bf16x8*)&Kb[n * 16 + lq][ks * 32 + lh * 8];
                s[n] = __builtin_amdgcn_mfma_f32_16x16x32_bf16(qa[ks], kf, s[n], 0, 0, 0);
            }

        const bool diag = (kvt == qt);
        #pragma unroll
        for (int n = 0; n < 4; ++n)
            #pragma unroll
            for (int j = 0; j < 4; ++j) {
                float p = sigmoid_half(s[n][j]);
                if (diag && (n * 16 + lq) > (w * 16 + lh * 4 + j)) p = 0.f;
                Pb[w][lh * 4 + j][n * 16 + lq] = (__bf16)p;
            }

        #pragma unroll
        for (int ks = 0; ks < 2; ++ks) {
            bf16x8 pf = *(const bf16x8*)&Pb[w][lq][ks * 32 + lh * 8];
            #pragma unroll
            for (int n = 0; n < 4; ++n) {
                bf16x8 vf = *(const bf16x8*)&Vt[n * 16 + lq][ks * 32 + lh * 8];
                o[n] = __builtin_amdgcn_mfma_f32_16x16x32_bf16(pf, vf, o[n], 0, 0, 0);
            }
        }
    }

    float* op = out + ((long)b * T_LEN + q0 + w * 16) * DIM + h * HD;
    #pragma unroll
    for (int n = 0; n < 4; ++n)
        #pragma unroll
        for (int j = 0; j < 4; ++j)
            op[(long)(lh * 4 + j) * DIM + n * 16 + lq] = o[n][j];
}

extern "C" void kernel_launch(void* const* d_in, const int* in_sizes, int n_in,
                              void* d_out, int out_size, void* d_ws, size_t ws_size,
                              hipStream_t stream) {
    (void)in_sizes; (void)n_in; (void)out_size;
    const float* x   = (const float*)d_in[0];
    const float* bvq = (const float*)d_in[1];
    const float* bvk = (const float*)d_in[2];
    const float* bvv = (const float*)d_in[3];
    float* out = (float*)d_out;

    const size_t XB_BYTES = (size_t)NB * T_LEN * DIM * sizeof(__bf16);  // 8 MB
    const size_t XT_BYTES = XB_BYTES;                                    // 8 MB

    if (ws_size < XB_BYTES + XT_BYTES) {
        mba_fallback<<<NB * NH * NQT, 256, 0, stream>>>(x, bvq, bvk, bvv, out);
        return;
    }

    __bf16* xb = (__bf16*)d_ws;
    __bf16* xt = xb + (size_t)NB * T_LEN * DIM;

    prep_kernel<<<NB * NQT * NH, 256, 0, stream>>>(x, bvv, xb, xt);
    mba_main<<<16 * 32, 256, 0, stream>>>(xb, xt, bvq, bvk, out);
}